// Round 1
// baseline (303.716 us; speedup 1.0000x reference)
//
#include <hip/hip_runtime.h>

#define HW (512 * 512)
#define GD 200
#define NS 9
#define NF 8

__global__ __launch_bounds__(256) void fusion_gather_kernel(
    const float* __restrict__ vpoints,
    const float* __restrict__ veye,
    const float* __restrict__ grid,
    const float* __restrict__ empty_value,
    float* __restrict__ out_values,   // [72][HW]
    float* __restrict__ out_pn,       // [HW][9][3]
    float* __restrict__ out_dirs)     // [HW][3]
{
    int n = blockIdx.x * blockDim.x + threadIdx.x;
    if (n >= HW) return;

    float px = vpoints[n * 3 + 0];
    float py = vpoints[n * 3 + 1];
    float pz = vpoints[n * 3 + 2];
    float ex = veye[0], ey = veye[1], ez = veye[2];

    float dx = px - ex, dy = py - ey, dz = pz - ez;
    float inv = 1.0f / sqrtf(dx * dx + dy * dy + dz * dz);
    dx *= inv; dy *= inv; dz *= inv;

    out_dirs[n * 3 + 0] = dx;
    out_dirs[n * 3 + 1] = dy;
    out_dirs[n * 3 + 2] = dz;

    float ev[NF];
#pragma unroll
    for (int f = 0; f < NF; ++f) ev[f] = empty_value[f];

    const float4* g4 = (const float4*)grid;

#pragma unroll
    for (int s = 0; s < NS; ++s) {
        float off = (float)(s - NS / 2);
        float cx = px + off * dx;
        float cy = py + off * dy;
        float cz = pz + off * dz;

        // points_normalized = cv - (floor(cv) + 0.5)
        out_pn[(n * NS + s) * 3 + 0] = cx - (floorf(cx) + 0.5f);
        out_pn[(n * NS + s) * 3 + 1] = cy - (floorf(cy) + 0.5f);
        out_pn[(n * NS + s) * 3 + 2] = cz - (floorf(cz) + 0.5f);

        bool valid = (cx >= 0.0f) && (cx < (float)GD) &&
                     (cy >= 0.0f) && (cy < (float)GD) &&
                     (cz >= 0.0f) && (cz < (float)GD);

        float ft[NF];
#pragma unroll
        for (int f = 0; f < NF; ++f) ft[f] = ev[f];

        if (valid) {
            // reference: p = pts + 1 (into edge-padded grid), base = floor(p)
            float p0 = cx + 1.0f, p1 = cy + 1.0f, p2 = cz + 1.0f;
            float f0 = floorf(p0), f1 = floorf(p1), f2 = floorf(p2);
            float d0 = p0 - f0, d1 = p1 - f1, d2 = p2 - f2;
            int bx = (int)f0, by = (int)f1, bz = (int)f2;
            // padded index i maps to grid[clamp(i-1, 0, 199)]; bx in [1,200]
            int X0 = bx - 1, X1 = min(bx, GD - 1);
            int Y0 = by - 1, Y1 = min(by, GD - 1);
            int Z0 = bz - 1, Z1 = min(bz, GD - 1);

            float wz0 = 1.0f - d2, wz1 = d2;

            float acc[NF];
#pragma unroll
            for (int f = 0; f < NF; ++f) acc[f] = 0.0f;

#pragma unroll
            for (int ix = 0; ix < 2; ++ix) {
                int X = ix ? X1 : X0;
                float wx = ix ? d0 : (1.0f - d0);
#pragma unroll
                for (int iy = 0; iy < 2; ++iy) {
                    int Y = iy ? Y1 : Y0;
                    float wy = iy ? d1 : (1.0f - d1);
                    float wxy = wx * wy;
                    int rowbase = (X * GD + Y) * GD;
                    float4 a0 = g4[(size_t)(rowbase + Z0) * 2 + 0];
                    float4 a1 = g4[(size_t)(rowbase + Z0) * 2 + 1];
                    float4 b0 = g4[(size_t)(rowbase + Z1) * 2 + 0];
                    float4 b1 = g4[(size_t)(rowbase + Z1) * 2 + 1];
                    float w0 = wxy * wz0, w1 = wxy * wz1;
                    acc[0] += w0 * a0.x + w1 * b0.x;
                    acc[1] += w0 * a0.y + w1 * b0.y;
                    acc[2] += w0 * a0.z + w1 * b0.z;
                    acc[3] += w0 * a0.w + w1 * b0.w;
                    acc[4] += w0 * a1.x + w1 * b1.x;
                    acc[5] += w0 * a1.y + w1 * b1.y;
                    acc[6] += w0 * a1.z + w1 * b1.z;
                    acc[7] += w0 * a1.w + w1 * b1.w;
                }
            }
#pragma unroll
            for (int f = 0; f < NF; ++f) ft[f] = acc[f];
        }

        // values[(s*8+f)][n] — coalesced across the wave
#pragma unroll
        for (int f = 0; f < NF; ++f)
            out_values[(size_t)(s * NF + f) * HW + n] = ft[f];
    }
}

extern "C" void kernel_launch(void* const* d_in, const int* in_sizes, int n_in,
                              void* d_out, int out_size, void* d_ws, size_t ws_size,
                              hipStream_t stream) {
    const float* vpoints = (const float*)d_in[0];
    const float* veye = (const float*)d_in[1];
    // d_in[2] = depth: unused by the computation (only its shape matters)
    const float* grid = (const float*)d_in[3];
    const float* empty_value = (const float*)d_in[4];

    float* out = (float*)d_out;
    float* out_values = out;                          // 72 * HW
    float* out_pn = out + (size_t)NS * NF * HW;       // HW * 9 * 3
    float* out_dirs = out_pn + (size_t)HW * NS * 3;   // HW * 3

    dim3 block(256);
    dim3 grid_dim((HW + 255) / 256);
    hipLaunchKernelGGL(fusion_gather_kernel, grid_dim, block, 0, stream,
                       vpoints, veye, grid, empty_value,
                       out_values, out_pn, out_dirs);
}

// Round 2
// 187.308 us; speedup vs baseline: 1.6215x; 1.6215x over previous
//
#include <hip/hip_runtime.h>

#define HW (512 * 512)
#define GD 200
#define NS 9
#define NF 8
#define NPB 64              // rays per block
#define BT (NPB * NS)       // 576 threads = 9 waves; wave = sample, lane = ray

__global__ __launch_bounds__(BT) void fusion_gather_kernel(
    const float* __restrict__ vpoints,
    const float* __restrict__ veye,
    const float* __restrict__ grid,
    const float* __restrict__ empty_value,
    float* __restrict__ out_values,   // [72][HW]
    float* __restrict__ out_pn,       // [HW][9][3]
    float* __restrict__ out_dirs)     // [HW][3]
{
    __shared__ float pnbuf[NPB * NS * 3];   // 6912 B, [i][s][c]
    __shared__ float dirbuf[NPB * 3];       // 768 B

    int tid = threadIdx.x;
    int s = tid >> 6;          // sample index 0..8 (= wave id)
    int i = tid & 63;          // ray-within-block (= lane)
    int n0 = blockIdx.x * NPB;
    int n = n0 + i;

    float px = vpoints[n * 3 + 0];
    float py = vpoints[n * 3 + 1];
    float pz = vpoints[n * 3 + 2];
    float ex = veye[0], ey = veye[1], ez = veye[2];

    float dx = px - ex, dy = py - ey, dz = pz - ez;
    float inv = 1.0f / sqrtf(dx * dx + dy * dy + dz * dz);
    dx *= inv; dy *= inv; dz *= inv;

    if (s == 4) {
        dirbuf[i * 3 + 0] = dx;
        dirbuf[i * 3 + 1] = dy;
        dirbuf[i * 3 + 2] = dz;
    }

    float off = (float)(s - NS / 2);
    float cx = px + off * dx;
    float cy = py + off * dy;
    float cz = pz + off * dz;

    // points_normalized = cv - (floor(cv) + 0.5); stride 27 across lanes -> 27⊥32, bank-conflict-free
    pnbuf[i * 27 + s * 3 + 0] = cx - (floorf(cx) + 0.5f);
    pnbuf[i * 27 + s * 3 + 1] = cy - (floorf(cy) + 0.5f);
    pnbuf[i * 27 + s * 3 + 2] = cz - (floorf(cz) + 0.5f);

    bool valid = (cx >= 0.0f) && (cx < (float)GD) &&
                 (cy >= 0.0f) && (cy < (float)GD) &&
                 (cz >= 0.0f) && (cz < (float)GD);

    float ft[NF];
#pragma unroll
    for (int f = 0; f < NF; ++f) ft[f] = empty_value[f];

    const float4* g4 = (const float4*)grid;

    if (valid) {
        // reference: p = pts + 1 (into edge-padded grid), base = floor(p)
        float p0 = cx + 1.0f, p1 = cy + 1.0f, p2 = cz + 1.0f;
        float f0 = floorf(p0), f1 = floorf(p1), f2 = floorf(p2);
        float d0 = p0 - f0, d1 = p1 - f1, d2 = p2 - f2;
        int bx = (int)f0, by = (int)f1, bz = (int)f2;
        // padded index i maps to grid[clamp(i-1, 0, 199)]; bx in [1,200]
        int X0 = bx - 1, X1 = min(bx, GD - 1);
        int Y0 = by - 1, Y1 = min(by, GD - 1);
        int Z0 = bz - 1, Z1 = min(bz, GD - 1);

        float wz0 = 1.0f - d2, wz1 = d2;

        float acc[NF];
#pragma unroll
        for (int f = 0; f < NF; ++f) acc[f] = 0.0f;

#pragma unroll
        for (int ix = 0; ix < 2; ++ix) {
            int X = ix ? X1 : X0;
            float wx = ix ? d0 : (1.0f - d0);
#pragma unroll
            for (int iy = 0; iy < 2; ++iy) {
                int Y = iy ? Y1 : Y0;
                float wy = iy ? d1 : (1.0f - d1);
                float wxy = wx * wy;
                int rowbase = (X * GD + Y) * GD;
                float4 a0 = g4[(size_t)(rowbase + Z0) * 2 + 0];
                float4 a1 = g4[(size_t)(rowbase + Z0) * 2 + 1];
                float4 b0 = g4[(size_t)(rowbase + Z1) * 2 + 0];
                float4 b1 = g4[(size_t)(rowbase + Z1) * 2 + 1];
                float w0 = wxy * wz0, w1 = wxy * wz1;
                acc[0] += w0 * a0.x + w1 * b0.x;
                acc[1] += w0 * a0.y + w1 * b0.y;
                acc[2] += w0 * a0.z + w1 * b0.z;
                acc[3] += w0 * a0.w + w1 * b0.w;
                acc[4] += w0 * a1.x + w1 * b1.x;
                acc[5] += w0 * a1.y + w1 * b1.y;
                acc[6] += w0 * a1.z + w1 * b1.z;
                acc[7] += w0 * a1.w + w1 * b1.w;
            }
        }
#pragma unroll
        for (int f = 0; f < NF; ++f) ft[f] = acc[f];
    }

    // values[(s*8+f)][n] — each wave has fixed s, consecutive n -> coalesced 256 B stores
#pragma unroll
    for (int f = 0; f < NF; ++f)
        __builtin_nontemporal_store(ft[f], &out_values[(size_t)(s * NF + f) * HW + n]);

    __syncthreads();

    // block-coalesced writeout of pn (1728 floats = 3 per thread) and dirs (192 floats)
    const size_t pn_base = (size_t)n0 * (NS * 3);
#pragma unroll
    for (int k = 0; k < 3; ++k) {
        int idx = tid + k * BT;
        __builtin_nontemporal_store(pnbuf[idx], &out_pn[pn_base + idx]);
    }
    if (tid < NPB * 3)
        __builtin_nontemporal_store(dirbuf[tid], &out_dirs[(size_t)n0 * 3 + tid]);
}

extern "C" void kernel_launch(void* const* d_in, const int* in_sizes, int n_in,
                              void* d_out, int out_size, void* d_ws, size_t ws_size,
                              hipStream_t stream) {
    const float* vpoints = (const float*)d_in[0];
    const float* veye = (const float*)d_in[1];
    // d_in[2] = depth: unused by the computation (only its shape matters)
    const float* grid = (const float*)d_in[3];
    const float* empty_value = (const float*)d_in[4];

    float* out = (float*)d_out;
    float* out_values = out;                          // 72 * HW
    float* out_pn = out + (size_t)NS * NF * HW;       // HW * 9 * 3
    float* out_dirs = out_pn + (size_t)HW * NS * 3;   // HW * 3

    dim3 block(BT);
    dim3 grid_dim(HW / NPB);
    hipLaunchKernelGGL(fusion_gather_kernel, grid_dim, block, 0, stream,
                       vpoints, veye, grid, empty_value,
                       out_values, out_pn, out_dirs);
}